// Round 6
// baseline (199.407 us; speedup 1.0000x reference)
//
#include <hip/hip_runtime.h>
#include <hip/hip_bf16.h>

#define B_ 2
#define S_ 2048
#define D_ 1024
#define H_ 16
#define HD_ 64
#define KDIM 1024

typedef __attribute__((ext_vector_type(8))) short s16x8;
typedef __attribute__((ext_vector_type(8))) __bf16 bf16x8;
typedef __attribute__((ext_vector_type(4))) float f32x4;
typedef __attribute__((ext_vector_type(16))) float f32x16;
typedef __attribute__((ext_vector_type(4))) unsigned short u16x4;

__device__ __forceinline__ unsigned short f2bf(float f) {
  union { __bf16 b; unsigned short u; } v;
  v.b = (__bf16)f;
  return v.u;
}

__device__ __forceinline__ unsigned pk2(float lo, float hi) {
  union { unsigned short s[2]; unsigned u; } r;
  r.s[0] = f2bf(lo); r.s[1] = f2bf(hi);
  return r.u;
}

// permlane32_swap(a, b): HW swaps a[32+j] <-> b[j].
__device__ __forceinline__ void plswap2(unsigned& a_out, unsigned& b_out,
                                        unsigned a, unsigned b) {
  auto rr = __builtin_amdgcn_permlane32_swap(a, b, false, false);
  unsigned out[2];
  __builtin_memcpy(out, &rr, 8);
  a_out = out[0];
  b_out = out[1];
}

#define MFMA16(a, b, c) __builtin_amdgcn_mfma_f32_16x16x32_bf16((a), (b), (c), 0, 0, 0)
#define MFMA32(a, b, c) __builtin_amdgcn_mfma_f32_32x32x16_bf16((a), (b), (c), 0, 0, 0)

__device__ __forceinline__ void gll16(const void* g, void* l) {
  __builtin_amdgcn_global_load_lds(
      (const __attribute__((address_space(1))) void*)g,
      (__attribute__((address_space(3))) void*)l, 16, 0, 0);
}

// ---------------- X fp32 -> bf16
__global__ __launch_bounds__(256) void x2bf(const float* __restrict__ X,
                                            unsigned short* __restrict__ Xb) {
  const int i = (blockIdx.x * 256 + threadIdx.x) * 8;
  const float4 a = *reinterpret_cast<const float4*>(X + i);
  const float4 b = *reinterpret_cast<const float4*>(X + i + 4);
  u16x4 lo = {f2bf(a.x), f2bf(a.y), f2bf(a.z), f2bf(a.w)};
  u16x4 hi = {f2bf(b.x), f2bf(b.y), f2bf(b.z), f2bf(b.w)};
  *reinterpret_cast<u16x4*>(Xb + i) = lo;
  *reinterpret_cast<u16x4*>(Xb + i + 4) = hi;
}

// ---------------- transpose+convert: W[1024][N] fp32 -> Wt[N][1024] bf16
__global__ __launch_bounds__(256) void transpose_w(const float* __restrict__ W,
                                                   unsigned short* __restrict__ Wt,
                                                   int N) {
  __shared__ float T[64][65];
  const int k0 = blockIdx.y * 64, n0 = blockIdx.x * 64;
  const int t = threadIdx.x;
  const int lr = t >> 4, lc = (t & 15) * 4;
#pragma unroll
  for (int p = 0; p < 4; ++p) {
    const int r = lr + p * 16;
    const float4 v = *reinterpret_cast<const float4*>(W + (size_t)(k0 + r) * N + n0 + lc);
    T[r][lc + 0] = v.x; T[r][lc + 1] = v.y; T[r][lc + 2] = v.z; T[r][lc + 3] = v.w;
  }
  __syncthreads();
  const int wn = t >> 4, wk = (t & 15) * 4;
#pragma unroll
  for (int p = 0; p < 4; ++p) {
    const int n = wn + p * 16;
    u16x4 o = {f2bf(T[wk + 0][n]), f2bf(T[wk + 1][n]), f2bf(T[wk + 2][n]), f2bf(T[wk + 3][n])};
    *reinterpret_cast<u16x4*>(Wt + (size_t)(n0 + n) * 1024 + k0 + wk) = o;
  }
}

// ---------------- V[b,h,s,hd] -> Vt[b,h,hd,s]
__global__ __launch_bounds__(256) void vtrans(const unsigned short* __restrict__ Vb,
                                              unsigned short* __restrict__ Vt) {
  __shared__ unsigned short T[64][72];
  const int s0 = blockIdx.x * 64;
  const int bh = blockIdx.y;
  const int t = threadIdx.x;
  const size_t base = (size_t)bh * (S_ * HD_);
  const int r = t >> 3, c8 = (t & 7) * 8;
#pragma unroll
  for (int p = 0; p < 2; ++p)
    *reinterpret_cast<s16x8*>(&T[r + p * 32][c8]) =
        *reinterpret_cast<const s16x8*>(Vb + base + (size_t)(s0 + r + p * 32) * HD_ + c8);
  __syncthreads();
  const int hd = t & 63, sg = (t >> 6) * 8;
#pragma unroll
  for (int p = 0; p < 2; ++p) {
    unsigned short tmp[8];
#pragma unroll
    for (int j = 0; j < 8; ++j) tmp[j] = T[sg + p * 32 + j][hd];
    *reinterpret_cast<s16x8*>(Vt + base + (size_t)hd * S_ + s0 + sg + p * 32) =
        *reinterpret_cast<s16x8*>(tmp);
  }
}

// ---------------- QKV projection (gll16-staged) -> Q/K/V [b,h,s,hd]
__global__ __launch_bounds__(256) void gemm_qkv(
    const unsigned short* __restrict__ Xb, const unsigned short* __restrict__ WT,
    const float* __restrict__ bias,
    unsigned short* __restrict__ Qo, unsigned short* __restrict__ Ko,
    unsigned short* __restrict__ Vo) {
  __shared__ __align__(16) unsigned short As[128 * 64];
  __shared__ __align__(16) unsigned short Bs[128 * 64];
  const int m0 = blockIdx.y * 128, n0 = blockIdx.x * 128;
  const int t = threadIdx.x;
  const int lane = t & 63, wid = t >> 6;
  const int wr = wid >> 1, wc = wid & 1;
  const int l15 = lane & 15, l16 = lane >> 4;
  const int srow = lane >> 3, scol = ((lane & 7) ^ srow) << 3;
  f32x4 acc[4][4] = {};
  for (int k0 = 0; k0 < KDIM; k0 += 64) {
#pragma unroll
    for (int c = 0; c < 4; ++c) {
      const int r8 = wid * 32 + c * 8;
      gll16(Xb + (size_t)(m0 + r8 + srow) * KDIM + k0 + scol, &As[r8 * 64]);
      gll16(WT + (size_t)(n0 + r8 + srow) * KDIM + k0 + scol, &Bs[r8 * 64]);
    }
    __syncthreads();
    const int key = (l15 & 7) << 4;
    const char* ab = (const char*)As + (wr * 64 + l15) * 128;
    const char* bb = (const char*)Bs + (wc * 64 + l15) * 128;
#pragma unroll
    for (int ks = 0; ks < 2; ++ks) {
      bf16x8 af[4], bfr[4];
#pragma unroll
      for (int m = 0; m < 4; ++m)
        af[m] = *(const bf16x8*)(ab + m * 2048 + ((ks * 64 + l16 * 16) ^ key));
#pragma unroll
      for (int n = 0; n < 4; ++n)
        bfr[n] = *(const bf16x8*)(bb + n * 2048 + ((ks * 64 + l16 * 16) ^ key));
#pragma unroll
      for (int m = 0; m < 4; ++m)
#pragma unroll
        for (int n = 0; n < 4; ++n)
          acc[m][n] = MFMA16(af[m], bfr[n], acc[m][n]);
    }
    __syncthreads();
  }
#pragma unroll
  for (int n = 0; n < 4; ++n) {
    const int col = n0 + wc * 64 + n * 16 + l15;
    const float bv = bias[col];
    const int which = col >> 10;
    const int dcol = col & 1023;
    unsigned short* dst = (which == 0) ? Qo : (which == 1) ? Ko : Vo;
    const int hh = dcol >> 6, hd = dcol & 63;
#pragma unroll
    for (int m = 0; m < 4; ++m) {
#pragma unroll
      for (int j = 0; j < 4; ++j) {
        const int row = m0 + wr * 64 + m * 16 + l16 * 4 + j;
        const int bb2 = row >> 11, s = row & 2047;
        dst[(((size_t)bb2 * H_ + hh) * S_ + s) * HD_ + hd] = f2bf(acc[m][n][j] + bv);
      }
    }
  }
}

// ---------------- Flash attention: 1-wave blocks, direct-global K/V, no barriers.
// 2048 blocks: xcd = bi&7 -> 4 heads/XCD (L2-resident K/V); qt heavy-first.
__global__ __launch_bounds__(64, 3) void attn(
    const unsigned short* __restrict__ Qb, const unsigned short* __restrict__ Kb,
    const unsigned short* __restrict__ Vt, unsigned short* __restrict__ Cxt) {
  __shared__ float obuf[32 * 64];  // epilogue transpose scratch
  const int bi = blockIdx.x;
  const int xcd = bi & 7, slot = bi >> 3;
  const int bh = xcd * 4 + (slot & 3);
  const int qt = 63 - (slot >> 2);  // 32-row q-tile, heavy first
  const int lane = threadIdx.x;
  const int l31 = lane & 31, h = lane >> 5;
  const int h8 = h * 8, h4 = h * 4;
  const size_t base = (size_t)bh * (S_ * HD_);
  const int qrow0 = qt * 32;
  const int ntile = ((qrow0 + 31) >> 6) + 1;
  const float NEG = -1e30f;
  const float SCALE = 0.18033688011112042f;  // (1/8)*log2(e)

  bf16x8 qf[4];
  {
    const unsigned short* qp = Qb + base + (size_t)(qrow0 + l31) * HD_ + h8;
#pragma unroll
    for (int ks = 0; ks < 4; ++ks) qf[ks] = *reinterpret_cast<const bf16x8*>(qp + ks * 16);
  }
  f32x16 o0 = {}, o1 = {};
  float mrow = NEG, lrow = 0.f;

  for (int kt = 0; kt < ntile; ++kt) {
    const int kv0 = kt * 64;
    const bool full2 = (kv0 + 32 <= qrow0 + 31);  // second 32-kv half has valid cols
    // ---- K fragments direct from global (rows kv0+l31 / +32+l31)
    const unsigned short* kp = Kb + base + (size_t)(kv0 + l31) * HD_ + h8;
    bf16x8 ka[4], kb[4];
#pragma unroll
    for (int ks = 0; ks < 4; ++ks) ka[ks] = *reinterpret_cast<const bf16x8*>(kp + ks * 16);
    if (full2) {
#pragma unroll
      for (int ks = 0; ks < 4; ++ks)
        kb[ks] = *reinterpret_cast<const bf16x8*>(kp + 32 * HD_ + ks * 16);
    }
    // ---- V fragments (independent of softmax -> overlap)
    const unsigned short* vp0 = Vt + base + (size_t)l31 * S_ + kv0 + h8;
    const unsigned short* vp1 = vp0 + (size_t)32 * S_;
    bf16x8 vf0[4], vf1[4];
    const int nks = full2 ? 4 : 2;
#pragma unroll
    for (int ks = 0; ks < 4; ++ks)
      if (ks < nks) {
        vf0[ks] = *reinterpret_cast<const bf16x8*>(vp0 + ks * 16);
        vf1[ks] = *reinterpret_cast<const bf16x8*>(vp1 + ks * 16);
      }
    // ---- QK^T (swapped): C col = q = l31
    f32x16 s0 = {}, s1 = {};
    __builtin_amdgcn_s_setprio(1);
#pragma unroll
    for (int ks = 0; ks < 4; ++ks) s0 = MFMA32(ka[ks], qf[ks], s0);
    if (full2) {
#pragma unroll
      for (int ks = 0; ks < 4; ++ks) s1 = MFMA32(kb[ks], qf[ks], s1);
    }
    __builtin_amdgcn_s_setprio(0);
    // ---- scale (+ mask on diagonal tiles)
    if (kv0 + 63 > qrow0) {
      const int lim0 = qrow0 + l31 - kv0;
      const int lim1 = lim0 - 32;
#pragma unroll
      for (int r = 0; r < 16; ++r) {
        const int cr = (r & 3) + 8 * (r >> 2) + h4;
        s0[r] = (cr > lim0) ? NEG : s0[r] * SCALE;
        if (full2) s1[r] = (cr > lim1) ? NEG : s1[r] * SCALE;
      }
    } else {
#pragma unroll
      for (int r = 0; r < 16; ++r) { s0[r] *= SCALE; s1[r] *= SCALE; }
    }
    // ---- row max
    float m8[8];
#pragma unroll
    for (int r = 0; r < 8; ++r) m8[r] = fmaxf(s0[r], s0[r + 8]);
    if (full2) {
#pragma unroll
      for (int r = 0; r < 8; ++r) m8[r] = fmaxf(m8[r], fmaxf(s1[r], s1[r + 8]));
    }
#pragma unroll
    for (int st = 4; st > 0; st >>= 1)
#pragma unroll
      for (int r = 0; r < st; ++r) m8[r] = fmaxf(m8[r], m8[r + st]);
    const float pmax = fmaxf(m8[0], __shfl_xor(m8[0], 32));
    // ---- defer-rescale (THR=8, exp2 domain)
    if (!__all(pmax - mrow <= 8.f)) {
      const float mn = fmaxf(mrow, pmax);
      const float al = exp2f(mrow - mn);
      mrow = mn;
      lrow *= al;
#pragma unroll
      for (int r = 0; r < 16; ++r) { o0[r] *= al; o1[r] *= al; }
    }
    // ---- exp + row sum
#pragma unroll
    for (int r = 0; r < 16; ++r) s0[r] = exp2f(s0[r] - mrow);
    if (full2) {
#pragma unroll
      for (int r = 0; r < 16; ++r) s1[r] = exp2f(s1[r] - mrow);
    }
    float p8[8];
#pragma unroll
    for (int r = 0; r < 8; ++r) p8[r] = s0[r] + s0[r + 8];
    if (full2) {
#pragma unroll
      for (int r = 0; r < 8; ++r) p8[r] += s1[r] + s1[r + 8];
    }
#pragma unroll
    for (int st = 4; st > 0; st >>= 1)
#pragma unroll
      for (int r = 0; r < st; ++r) p8[r] += p8[r + st];
    lrow += p8[0] + __shfl_xor(p8[0], 32);
    // ---- pack P -> bf16 B-fragments: pa[ks] slot i = P[q=l31][kv=ks*16+h8+i]
    bf16x8 pa[4];
    {
      union { unsigned u[4]; bf16x8 v; } uu;
      unsigned a0, a1, a2, a3, w0, w1, w2, w3;
      w0 = pk2(s0[0], s0[1]); w1 = pk2(s0[2], s0[3]);
      w2 = pk2(s0[4], s0[5]); w3 = pk2(s0[6], s0[7]);
      plswap2(a0, a2, w0, w2); plswap2(a1, a3, w1, w3);
      uu.u[0] = a0; uu.u[1] = a1; uu.u[2] = a2; uu.u[3] = a3; pa[0] = uu.v;
      w0 = pk2(s0[8], s0[9]); w1 = pk2(s0[10], s0[11]);
      w2 = pk2(s0[12], s0[13]); w3 = pk2(s0[14], s0[15]);
      plswap2(a0, a2, w0, w2); plswap2(a1, a3, w1, w3);
      uu.u[0] = a0; uu.u[1] = a1; uu.u[2] = a2; uu.u[3] = a3; pa[1] = uu.v;
      if (full2) {
        w0 = pk2(s1[0], s1[1]); w1 = pk2(s1[2], s1[3]);
        w2 = pk2(s1[4], s1[5]); w3 = pk2(s1[6], s1[7]);
        plswap2(a0, a2, w0, w2); plswap2(a1, a3, w1, w3);
        uu.u[0] = a0; uu.u[1] = a1; uu.u[2] = a2; uu.u[3] = a3; pa[2] = uu.v;
        w0 = pk2(s1[8], s1[9]); w1 = pk2(s1[10], s1[11]);
        w2 = pk2(s1[12], s1[13]); w3 = pk2(s1[14], s1[15]);
        plswap2(a0, a2, w0, w2); plswap2(a1, a3, w1, w3);
        uu.u[0] = a0; uu.u[1] = a1; uu.u[2] = a2; uu.u[3] = a3; pa[3] = uu.v;
      }
    }
    // ---- PV: O^T = V^T * P^T
    __builtin_amdgcn_s_setprio(1);
#pragma unroll
    for (int ks = 0; ks < 4; ++ks)
      if (ks < nks) {
        o0 = MFMA32(vf0[ks], pa[ks], o0);
        o1 = MFMA32(vf1[ks], pa[ks], o1);
      }
    __builtin_amdgcn_s_setprio(0);
  }
  // ---- epilogue: O^T -> LDS -> coalesced bf16 stores (Cxt [b,h,s,hd])
  const float rl = 1.0f / lrow;
#pragma unroll
  for (int r = 0; r < 16; ++r) {
    const int cr = (r & 3) + 8 * (r >> 2) + h4;
    obuf[l31 * 64 + (cr ^ ((l31 & 7) << 2))] = o0[r] * rl;
    obuf[l31 * 64 + ((32 + cr) ^ ((l31 & 7) << 2))] = o1[r] * rl;
  }
  __syncthreads();
#pragma unroll
  for (int p = 0; p < 8; ++p) {
    const int r = (lane >> 4) + p * 4;
    const int ce = ((lane & 15) * 4) ^ ((r & 7) << 2);
    const f32x4 v = *reinterpret_cast<const f32x4*>(&obuf[r * 64 + ce]);
    u16x4 w = {f2bf(v[0]), f2bf(v[1]), f2bf(v[2]), f2bf(v[3])};
    *reinterpret_cast<u16x4*>(&Cxt[base + (size_t)(qrow0 + r) * HD_ + (lane & 15) * 4]) = w;
  }
}

// ---------------- Output projection (gll16-staged): out = Ctx @ WoT^T + bias (fp32)
// Ctx head-blocked [b][h][s][hd]; K-step 64 = one head plane.
__global__ __launch_bounds__(256) void gemm_out(
    const unsigned short* __restrict__ Cxt, const unsigned short* __restrict__ WT,
    const float* __restrict__ bias, float* __restrict__ out) {
  constexpr int NM = 1024;
  __shared__ __align__(16) unsigned short As[128 * 64];
  __shared__ __align__(16) unsigned short Bs[128 * 64];
  const int m0 = blockIdx.y * 128, n0 = blockIdx.x * 128;
  const int t = threadIdx.x;
  const int lane = t & 63, wid = t >> 6;
  const int wr = wid >> 1, wc = wid & 1;
  const int l15 = lane & 15, l16 = lane >> 4;
  const int srow = lane >> 3, scol = ((lane & 7) ^ srow) << 3;
  f32x4 acc[4][4] = {};
  for (int k0 = 0; k0 < KDIM; k0 += 64) {
    const int head = k0 >> 6;
#pragma unroll
    for (int c = 0; c < 4; ++c) {
      const int r8 = wid * 32 + c * 8;
      const int gr = m0 + r8 + srow;
      const unsigned short* asrc =
          Cxt + ((((size_t)(gr >> 11) * H_ + head) << 11) + (gr & 2047)) * HD_ + scol;
      gll16(asrc, &As[r8 * 64]);
      gll16(WT + (size_t)(n0 + r8 + srow) * KDIM + k0 + scol, &Bs[r8 * 64]);
    }
    __syncthreads();
    const int key = (l15 & 7) << 4;
    const char* ab = (const char*)As + (wr * 64 + l15) * 128;
    const char* bb = (const char*)Bs + (wc * 64 + l15) * 128;
#pragma unroll
    for (int ks = 0; ks < 2; ++ks) {
      bf16x8 af[4], bfr[4];
#pragma unroll
      for (int m = 0; m < 4; ++m)
        af[m] = *(const bf16x8*)(ab + m * 2048 + ((ks * 64 + l16 * 16) ^ key));
#pragma unroll
      for (int n = 0; n < 4; ++n)
        bfr[n] = *(const bf16x8*)(bb + n * 2048 + ((ks * 64 + l16 * 16) ^ key));
#pragma unroll
      for (int m = 0; m < 4; ++m)
#pragma unroll
        for (int n = 0; n < 4; ++n)
          acc[m][n] = MFMA16(af[m], bfr[n], acc[m][n]);
    }
    __syncthreads();
  }
#pragma unroll
  for (int n = 0; n < 4; ++n) {
    const int col = n0 + wc * 64 + n * 16 + l15;
    const float bv = bias[col];
#pragma unroll
    for (int m = 0; m < 4; ++m) {
#pragma unroll
      for (int j = 0; j < 4; ++j) {
        const int row = m0 + wr * 64 + m * 16 + l16 * 4 + j;
        out[(size_t)row * NM + col] = acc[m][n][j] + bv;
      }
    }
  }
}

extern "C" void kernel_launch(void* const* d_in, const int* in_sizes, int n_in,
                              void* d_out, int out_size, void* d_ws, size_t ws_size,
                              hipStream_t stream) {
  const float* x = (const float*)d_in[0];
  const float* w_qkv = (const float*)d_in[1];
  const float* b_qkv = (const float*)d_in[2];
  const float* w_out = (const float*)d_in[3];
  const float* b_out = (const float*)d_in[4];
  float* out = (float*)d_out;

  const size_t NTOK = (size_t)B_ * H_ * S_ * HD_;  // 4,194,304 elements
  unsigned short* Qb = (unsigned short*)d_ws;
  unsigned short* Kb = Qb + NTOK;
  unsigned short* Vt = Kb + NTOK;                  // V transposed [b,h,hd,s]
  unsigned short* Vb = Vt + NTOK;                  // raw V (temp)
  unsigned short* WqT = Vb + NTOK;                 // [3072][1024]
  unsigned short* WoT = WqT + (size_t)3072 * 1024; // [1024][1024]
  unsigned short* Xbf = WoT + (size_t)1024 * 1024; // [4096][1024]
  unsigned short* Cxt = Xbf;                       // alias: Xbf dead before attn writes

  hipLaunchKernelGGL(x2bf, dim3(2048), dim3(256), 0, stream, x, Xbf);
  hipLaunchKernelGGL(transpose_w, dim3(48, 16), dim3(256), 0, stream, w_qkv, WqT, 3072);
  hipLaunchKernelGGL(transpose_w, dim3(16, 16), dim3(256), 0, stream, w_out, WoT, 1024);
  hipLaunchKernelGGL(gemm_qkv, dim3(24, 32), dim3(256), 0, stream, Xbf, WqT, b_qkv, Qb, Kb, Vb);
  hipLaunchKernelGGL(vtrans, dim3(32, 32), dim3(256), 0, stream, Vb, Vt);
  hipLaunchKernelGGL(attn, dim3(2048), dim3(64), 0, stream, Qb, Kb, Vt, Cxt);
  hipLaunchKernelGGL(gemm_out, dim3(8, 32), dim3(256), 0, stream, Cxt, WoT, b_out, out);
}

// Round 7
// 174.052 us; speedup vs baseline: 1.1457x; 1.1457x over previous
//
#include <hip/hip_runtime.h>
#include <hip/hip_bf16.h>

#define B_ 2
#define S_ 2048
#define D_ 1024
#define H_ 16
#define HD_ 64
#define KDIM 1024
#define QKVW 3072

typedef __attribute__((ext_vector_type(8))) short s16x8;
typedef __attribute__((ext_vector_type(8))) __bf16 bf16x8;
typedef __attribute__((ext_vector_type(4))) float f32x4;
typedef __attribute__((ext_vector_type(16))) float f32x16;
typedef __attribute__((ext_vector_type(4))) unsigned short u16x4;

__device__ __forceinline__ unsigned short f2bf(float f) {
  union { __bf16 b; unsigned short u; } v;
  v.b = (__bf16)f;
  return v.u;
}

__device__ __forceinline__ unsigned pk2(float lo, float hi) {
  union { unsigned short s[2]; unsigned u; } r;
  r.s[0] = f2bf(lo); r.s[1] = f2bf(hi);
  return r.u;
}

// permlane32_swap(a, b): HW swaps a[32+j] <-> b[j].
__device__ __forceinline__ void plswap2(unsigned& a_out, unsigned& b_out,
                                        unsigned a, unsigned b) {
  auto rr = __builtin_amdgcn_permlane32_swap(a, b, false, false);
  unsigned out[2];
  __builtin_memcpy(out, &rr, 8);
  a_out = out[0];
  b_out = out[1];
}

#define MFMA16(a, b, c) __builtin_amdgcn_mfma_f32_16x16x32_bf16((a), (b), (c), 0, 0, 0)
#define MFMA32(a, b, c) __builtin_amdgcn_mfma_f32_32x32x16_bf16((a), (b), (c), 0, 0, 0)

__device__ __forceinline__ void gll16(const void* g, void* l) {
  __builtin_amdgcn_global_load_lds(
      (const __attribute__((address_space(1))) void*)g,
      (__attribute__((address_space(3))) void*)l, 16, 0, 0);
}

// ---------------- X fp32 -> bf16
__global__ __launch_bounds__(256) void x2bf(const float* __restrict__ X,
                                            unsigned short* __restrict__ Xb) {
  const int i = (blockIdx.x * 256 + threadIdx.x) * 8;
  const float4 a = *reinterpret_cast<const float4*>(X + i);
  const float4 b = *reinterpret_cast<const float4*>(X + i + 4);
  u16x4 lo = {f2bf(a.x), f2bf(a.y), f2bf(a.z), f2bf(a.w)};
  u16x4 hi = {f2bf(b.x), f2bf(b.y), f2bf(b.z), f2bf(b.w)};
  *reinterpret_cast<u16x4*>(Xb + i) = lo;
  *reinterpret_cast<u16x4*>(Xb + i + 4) = hi;
}

// ---------------- transpose+convert: W[1024][N] fp32 -> Wt[N][1024] bf16
__global__ __launch_bounds__(256) void transpose_w(const float* __restrict__ W,
                                                   unsigned short* __restrict__ Wt,
                                                   int N) {
  __shared__ float T[64][65];
  const int k0 = blockIdx.y * 64, n0 = blockIdx.x * 64;
  const int t = threadIdx.x;
  const int lr = t >> 4, lc = (t & 15) * 4;
#pragma unroll
  for (int p = 0; p < 4; ++p) {
    const int r = lr + p * 16;
    const float4 v = *reinterpret_cast<const float4*>(W + (size_t)(k0 + r) * N + n0 + lc);
    T[r][lc + 0] = v.x; T[r][lc + 1] = v.y; T[r][lc + 2] = v.z; T[r][lc + 3] = v.w;
  }
  __syncthreads();
  const int wn = t >> 4, wk = (t & 15) * 4;
#pragma unroll
  for (int p = 0; p < 4; ++p) {
    const int n = wn + p * 16;
    u16x4 o = {f2bf(T[wk + 0][n]), f2bf(T[wk + 1][n]), f2bf(T[wk + 2][n]), f2bf(T[wk + 3][n])};
    *reinterpret_cast<u16x4*>(Wt + (size_t)(n0 + n) * 1024 + k0 + wk) = o;
  }
}

// ---------------- V columns of QKV -> Vt[b,h,hd,s]
__global__ __launch_bounds__(256) void vtrans(const unsigned short* __restrict__ QKVc,
                                              unsigned short* __restrict__ Vt) {
  __shared__ unsigned short T[64][72];
  const int s0 = blockIdx.x * 64;
  const int bh = blockIdx.y;
  const int bb = bh >> 4, hh = bh & 15;
  const int t = threadIdx.x;
  const size_t base = (size_t)bh * (S_ * HD_);
  const int r = t >> 3, c8 = (t & 7) * 8;
#pragma unroll
  for (int p = 0; p < 2; ++p)
    *reinterpret_cast<s16x8*>(&T[r + p * 32][c8]) =
        *reinterpret_cast<const s16x8*>(
            QKVc + (size_t)(bb * S_ + s0 + r + p * 32) * QKVW + 2048 + hh * 64 + c8);
  __syncthreads();
  const int hd = t & 63, sg = (t >> 6) * 8;
#pragma unroll
  for (int p = 0; p < 2; ++p) {
    unsigned short tmp[8];
#pragma unroll
    for (int j = 0; j < 8; ++j) tmp[j] = T[sg + p * 32 + j][hd];
    *reinterpret_cast<s16x8*>(Vt + base + (size_t)hd * S_ + s0 + sg + p * 32) =
        *reinterpret_cast<s16x8*>(tmp);
  }
}

// ---------------- QKV projection (gll16-staged) -> plain C[4096][3072] bf16 (+bias)
__global__ __launch_bounds__(256) void gemm_qkv(
    const unsigned short* __restrict__ Xb, const unsigned short* __restrict__ WT,
    const float* __restrict__ bias, unsigned short* __restrict__ Cq) {
  __shared__ __align__(16) unsigned short As[128 * 64];
  __shared__ __align__(16) unsigned short Bs[128 * 64];
  const int m0 = blockIdx.y * 128, n0 = blockIdx.x * 128;
  const int t = threadIdx.x;
  const int lane = t & 63, wid = t >> 6;
  const int wr = wid >> 1, wc = wid & 1;
  const int l15 = lane & 15, l16 = lane >> 4;
  const int srow = lane >> 3, scol = ((lane & 7) ^ srow) << 3;
  f32x4 acc[4][4] = {};
  for (int k0 = 0; k0 < KDIM; k0 += 64) {
#pragma unroll
    for (int c = 0; c < 4; ++c) {
      const int r8 = wid * 32 + c * 8;
      gll16(Xb + (size_t)(m0 + r8 + srow) * KDIM + k0 + scol, &As[r8 * 64]);
      gll16(WT + (size_t)(n0 + r8 + srow) * KDIM + k0 + scol, &Bs[r8 * 64]);
    }
    __syncthreads();
    const int key = (l15 & 7) << 4;
    const char* ab = (const char*)As + (wr * 64 + l15) * 128;
    const char* bb = (const char*)Bs + (wc * 64 + l15) * 128;
#pragma unroll
    for (int ks = 0; ks < 2; ++ks) {
      bf16x8 af[4], bfr[4];
#pragma unroll
      for (int m = 0; m < 4; ++m)
        af[m] = *(const bf16x8*)(ab + m * 2048 + ((ks * 64 + l16 * 16) ^ key));
#pragma unroll
      for (int n = 0; n < 4; ++n)
        bfr[n] = *(const bf16x8*)(bb + n * 2048 + ((ks * 64 + l16 * 16) ^ key));
#pragma unroll
      for (int m = 0; m < 4; ++m)
#pragma unroll
        for (int n = 0; n < 4; ++n)
          acc[m][n] = MFMA16(af[m], bfr[n], acc[m][n]);
    }
    __syncthreads();
  }
#pragma unroll
  for (int n = 0; n < 4; ++n) {
    const int col = n0 + wc * 64 + n * 16 + l15;
    const float bv = bias[col];
#pragma unroll
    for (int m = 0; m < 4; ++m) {
#pragma unroll
      for (int j = 0; j < 4; ++j) {
        const int row = m0 + wr * 64 + m * 16 + l16 * 4 + j;
        Cq[(size_t)row * QKVW + col] = f2bf(acc[m][n][j] + bv);
      }
    }
  }
}

// ---------------- Flash attention: 1-wave blocks, register-dbuf pipelined K/V.
// 2048 blocks: xcd = bi&7 -> 4 heads/XCD (L2-resident K/V); qt heavy-first.
__global__ __launch_bounds__(64, 2) void attn(
    const unsigned short* __restrict__ QKVc, const unsigned short* __restrict__ Vt,
    unsigned short* __restrict__ Cxt) {
  __shared__ float obuf[32 * 64];
  const int bi = blockIdx.x;
  const int xcd = bi & 7, slot = bi >> 3;
  const int bh = xcd * 4 + (slot & 3);
  const int qt = 63 - (slot >> 2);  // 32-row q-tile, heavy first
  const int lane = threadIdx.x;
  const int l31 = lane & 31, h = lane >> 5;
  const int h8 = h * 8, h4 = h * 4;
  const int bb = bh >> 4, hh = bh & 15;
  const size_t base = (size_t)bh * (S_ * HD_);
  const int qrow0 = qt * 32;
  const int ntile = ((qrow0 + 31) >> 6) + 1;
  const bool lastfull = (qt & 1);  // diag tile's second 32-kv half valid?
  const float NEG = -1e30f;
  const float SCALE = 0.18033688011112042f;  // (1/8)*log2(e)

  bf16x8 qf[4];
  {
    const unsigned short* qp =
        QKVc + (size_t)(bb * S_ + qrow0 + l31) * QKVW + hh * 64 + h8;
#pragma unroll
    for (int ks = 0; ks < 4; ++ks) qf[ks] = *reinterpret_cast<const bf16x8*>(qp + ks * 16);
  }
  f32x16 o0 = {}, o1 = {};
  float mrow = NEG, lrow = 0.f;

  bf16x8 kA[8], vA[8], kB[8], vB[8];

#define LOADKV(KD, VD, kvb)                                                          \
  do {                                                                               \
    const unsigned short* kp =                                                       \
        QKVc + (size_t)(bb * S_ + (kvb) + l31) * QKVW + 1024 + hh * 64 + h8;         \
    const unsigned short* vp = Vt + base + (size_t)l31 * S_ + (kvb) + h8;            \
    _Pragma("unroll") for (int ks = 0; ks < 4; ++ks) {                               \
      KD[ks] = *reinterpret_cast<const bf16x8*>(kp + ks * 16);                       \
      KD[4 + ks] = *reinterpret_cast<const bf16x8*>(kp + (size_t)32 * QKVW + ks * 16);\
      VD[ks] = *reinterpret_cast<const bf16x8*>(vp + ks * 16);                       \
      VD[4 + ks] = *reinterpret_cast<const bf16x8*>(vp + (size_t)32 * S_ + ks * 16); \
    }                                                                                \
  } while (0)

#define COMPUTE(KS, VS, kt)                                                          \
  do {                                                                               \
    const int kv0 = (kt) * 64;                                                       \
    const bool diag = ((kt) == ntile - 1);                                           \
    const bool full2 = !diag || lastfull;                                            \
    f32x16 s0 = {}, s1 = {};                                                         \
    __builtin_amdgcn_s_setprio(1);                                                   \
    _Pragma("unroll") for (int ks = 0; ks < 4; ++ks) s0 = MFMA32(KS[ks], qf[ks], s0);\
    if (full2) {                                                                     \
      _Pragma("unroll") for (int ks = 0; ks < 4; ++ks)                               \
        s1 = MFMA32(KS[4 + ks], qf[ks], s1);                                         \
    }                                                                                \
    __builtin_amdgcn_s_setprio(0);                                                   \
    if (diag) {                                                                      \
      const int lim0 = qrow0 + l31 - kv0;                                            \
      const int lim1 = lim0 - 32;                                                    \
      _Pragma("unroll") for (int r = 0; r < 16; ++r) {                               \
        const int cr = (r & 3) + 8 * (r >> 2) + h4;                                  \
        if (cr > lim0) s0[r] = NEG;                                                  \
        if (full2 && cr > lim1) s1[r] = NEG;                                         \
      }                                                                              \
    }                                                                                \
    float m8[8];                                                                     \
    _Pragma("unroll") for (int r = 0; r < 8; ++r) m8[r] = fmaxf(s0[r], s0[r + 8]);   \
    if (full2) {                                                                     \
      _Pragma("unroll") for (int r = 0; r < 8; ++r)                                  \
        m8[r] = fmaxf(m8[r], fmaxf(s1[r], s1[r + 8]));                               \
    }                                                                                \
    _Pragma("unroll") for (int st = 4; st > 0; st >>= 1)                             \
      _Pragma("unroll") for (int r = 0; r < st; ++r) m8[r] = fmaxf(m8[r], m8[r + st]);\
    const float pmax = fmaxf(m8[0], __shfl_xor(m8[0], 32)) * SCALE;                  \
    if (!__all(pmax - mrow <= 8.f)) {                                                \
      const float mn = fmaxf(mrow, pmax);                                            \
      const float al = exp2f(mrow - mn);                                             \
      mrow = mn;                                                                     \
      lrow *= al;                                                                    \
      _Pragma("unroll") for (int r = 0; r < 16; ++r) { o0[r] *= al; o1[r] *= al; }   \
    }                                                                                \
    _Pragma("unroll") for (int r = 0; r < 16; ++r)                                   \
      s0[r] = exp2f(fmaf(s0[r], SCALE, -mrow));                                      \
    if (full2) {                                                                     \
      _Pragma("unroll") for (int r = 0; r < 16; ++r)                                 \
        s1[r] = exp2f(fmaf(s1[r], SCALE, -mrow));                                    \
    }                                                                                \
    float p8[8];                                                                     \
    _Pragma("unroll") for (int r = 0; r < 8; ++r) p8[r] = s0[r] + s0[r + 8];         \
    if (full2) {                                                                     \
      _Pragma("unroll") for (int r = 0; r < 8; ++r) p8[r] += s1[r] + s1[r + 8];      \
    }                                                                                \
    _Pragma("unroll") for (int st = 4; st > 0; st >>= 1)                             \
      _Pragma("unroll") for (int r = 0; r < st; ++r) p8[r] += p8[r + st];            \
    lrow += p8[0] + __shfl_xor(p8[0], 32);                                           \
    bf16x8 pa[4];                                                                    \
    {                                                                                \
      union { unsigned u[4]; bf16x8 v; } uu;                                         \
      unsigned a0, a1, a2, a3, w0, w1, w2, w3;                                       \
      w0 = pk2(s0[0], s0[1]); w1 = pk2(s0[2], s0[3]);                                \
      w2 = pk2(s0[4], s0[5]); w3 = pk2(s0[6], s0[7]);                                \
      plswap2(a0, a2, w0, w2); plswap2(a1, a3, w1, w3);                              \
      uu.u[0] = a0; uu.u[1] = a1; uu.u[2] = a2; uu.u[3] = a3; pa[0] = uu.v;          \
      w0 = pk2(s0[8], s0[9]); w1 = pk2(s0[10], s0[11]);                              \
      w2 = pk2(s0[12], s0[13]); w3 = pk2(s0[14], s0[15]);                            \
      plswap2(a0, a2, w0, w2); plswap2(a1, a3, w1, w3);                              \
      uu.u[0] = a0; uu.u[1] = a1; uu.u[2] = a2; uu.u[3] = a3; pa[1] = uu.v;          \
      if (full2) {                                                                   \
        w0 = pk2(s1[0], s1[1]); w1 = pk2(s1[2], s1[3]);                              \
        w2 = pk2(s1[4], s1[5]); w3 = pk2(s1[6], s1[7]);                              \
        plswap2(a0, a2, w0, w2); plswap2(a1, a3, w1, w3);                            \
        uu.u[0] = a0; uu.u[1] = a1; uu.u[2] = a2; uu.u[3] = a3; pa[2] = uu.v;        \
        w0 = pk2(s1[8], s1[9]); w1 = pk2(s1[10], s1[11]);                            \
        w2 = pk2(s1[12], s1[13]); w3 = pk2(s1[14], s1[15]);                          \
        plswap2(a0, a2, w0, w2); plswap2(a1, a3, w1, w3);                            \
        uu.u[0] = a0; uu.u[1] = a1; uu.u[2] = a2; uu.u[3] = a3; pa[3] = uu.v;        \
      }                                                                              \
    }                                                                                \
    __builtin_amdgcn_s_setprio(1);                                                   \
    _Pragma("unroll") for (int ks = 0; ks < 4; ++ks)                                 \
      if (full2 || ks < 2) {                                                         \
        o0 = MFMA32(VS[ks], pa[ks], o0);                                             \
        o1 = MFMA32(VS[4 + ks], pa[ks], o1);                                         \
      }                                                                              \
    __builtin_amdgcn_s_setprio(0);                                                   \
  } while (0)

  LOADKV(kA, vA, 0);
  int kt = 0;
  while (true) {
    if (kt + 1 < ntile) LOADKV(kB, vB, (kt + 1) * 64);
    COMPUTE(kA, vA, kt);
    ++kt;
    if (kt >= ntile) break;
    if (kt + 1 < ntile) LOADKV(kA, vA, (kt + 1) * 64);
    COMPUTE(kB, vB, kt);
    ++kt;
    if (kt >= ntile) break;
  }

  // ---- epilogue: O^T -> LDS -> coalesced bf16 stores (Cxt [b,h,s,hd])
  const float rl = 1.0f / lrow;
#pragma unroll
  for (int r = 0; r < 16; ++r) {
    const int cr = (r & 3) + 8 * (r >> 2) + h4;
    obuf[l31 * 64 + (cr ^ ((l31 & 7) << 2))] = o0[r] * rl;
    obuf[l31 * 64 + ((32 + cr) ^ ((l31 & 7) << 2))] = o1[r] * rl;
  }
  __syncthreads();
#pragma unroll
  for (int p = 0; p < 8; ++p) {
    const int r = (lane >> 4) + p * 4;
    const int ce = ((lane & 15) * 4) ^ ((r & 7) << 2);
    const f32x4 v = *reinterpret_cast<const f32x4*>(&obuf[r * 64 + ce]);
    u16x4 w = {f2bf(v[0]), f2bf(v[1]), f2bf(v[2]), f2bf(v[3])};
    *reinterpret_cast<u16x4*>(&Cxt[base + (size_t)(qrow0 + r) * HD_ + (lane & 15) * 4]) = w;
  }
}

// ---------------- Output projection (gll16-staged): out = Ctx @ WoT^T + bias (fp32)
// Ctx head-blocked [b][h][s][hd]; K-step 64 = one head plane.
__global__ __launch_bounds__(256) void gemm_out(
    const unsigned short* __restrict__ Cxt, const unsigned short* __restrict__ WT,
    const float* __restrict__ bias, float* __restrict__ out) {
  constexpr int NM = 1024;
  __shared__ __align__(16) unsigned short As[128 * 64];
  __shared__ __align__(16) unsigned short Bs[128 * 64];
  const int m0 = blockIdx.y * 128, n0 = blockIdx.x * 128;
  const int t = threadIdx.x;
  const int lane = t & 63, wid = t >> 6;
  const int wr = wid >> 1, wc = wid & 1;
  const int l15 = lane & 15, l16 = lane >> 4;
  const int srow = lane >> 3, scol = ((lane & 7) ^ srow) << 3;
  f32x4 acc[4][4] = {};
  for (int k0 = 0; k0 < KDIM; k0 += 64) {
    const int head = k0 >> 6;
#pragma unroll
    for (int c = 0; c < 4; ++c) {
      const int r8 = wid * 32 + c * 8;
      const int gr = m0 + r8 + srow;
      const unsigned short* asrc =
          Cxt + ((((size_t)(gr >> 11) * H_ + head) << 11) + (gr & 2047)) * HD_ + scol;
      gll16(asrc, &As[r8 * 64]);
      gll16(WT + (size_t)(n0 + r8 + srow) * KDIM + k0 + scol, &Bs[r8 * 64]);
    }
    __syncthreads();
    const int key = (l15 & 7) << 4;
    const char* ab = (const char*)As + (wr * 64 + l15) * 128;
    const char* bb = (const char*)Bs + (wc * 64 + l15) * 128;
#pragma unroll
    for (int ks = 0; ks < 2; ++ks) {
      bf16x8 af[4], bfr[4];
#pragma unroll
      for (int m = 0; m < 4; ++m)
        af[m] = *(const bf16x8*)(ab + m * 2048 + ((ks * 64 + l16 * 16) ^ key));
#pragma unroll
      for (int n = 0; n < 4; ++n)
        bfr[n] = *(const bf16x8*)(bb + n * 2048 + ((ks * 64 + l16 * 16) ^ key));
#pragma unroll
      for (int m = 0; m < 4; ++m)
#pragma unroll
        for (int n = 0; n < 4; ++n)
          acc[m][n] = MFMA16(af[m], bfr[n], acc[m][n]);
    }
    __syncthreads();
  }
#pragma unroll
  for (int n = 0; n < 4; ++n) {
    const int col = n0 + wc * 64 + n * 16 + l15;
    const float bv = bias[col];
#pragma unroll
    for (int m = 0; m < 4; ++m) {
#pragma unroll
      for (int j = 0; j < 4; ++j) {
        const int row = m0 + wr * 64 + m * 16 + l16 * 4 + j;
        out[(size_t)row * NM + col] = acc[m][n][j] + bv;
      }
    }
  }
}

extern "C" void kernel_launch(void* const* d_in, const int* in_sizes, int n_in,
                              void* d_out, int out_size, void* d_ws, size_t ws_size,
                              hipStream_t stream) {
  const float* x = (const float*)d_in[0];
  const float* w_qkv = (const float*)d_in[1];
  const float* b_qkv = (const float*)d_in[2];
  const float* w_out = (const float*)d_in[3];
  const float* b_out = (const float*)d_in[4];
  float* out = (float*)d_out;

  const size_t NTOK = (size_t)B_ * H_ * S_ * HD_;  // 4,194,304 elements
  unsigned short* QKVc = (unsigned short*)d_ws;     // [4096][3072]
  unsigned short* Vt = QKVc + (size_t)4096 * QKVW;  // V transposed [b,h,hd,s]
  unsigned short* WqT = Vt + NTOK;                  // [3072][1024]
  unsigned short* WoT = WqT + (size_t)3072 * 1024;  // [1024][1024]
  unsigned short* Xbf = WoT + (size_t)1024 * 1024;  // [4096][1024]
  unsigned short* Cxt = Xbf;                        // alias: Xbf dead before attn writes

  hipLaunchKernelGGL(x2bf, dim3(2048), dim3(256), 0, stream, x, Xbf);
  hipLaunchKernelGGL(transpose_w, dim3(48, 16), dim3(256), 0, stream, w_qkv, WqT, 3072);
  hipLaunchKernelGGL(transpose_w, dim3(16, 16), dim3(256), 0, stream, w_out, WoT, 1024);
  hipLaunchKernelGGL(gemm_qkv, dim3(24, 32), dim3(256), 0, stream, Xbf, WqT, b_qkv, QKVc);
  hipLaunchKernelGGL(vtrans, dim3(32, 32), dim3(256), 0, stream, QKVc, Vt);
  hipLaunchKernelGGL(attn, dim3(2048), dim3(64), 0, stream, QKVc, Vt, Cxt);
  hipLaunchKernelGGL(gemm_out, dim3(8, 32), dim3(256), 0, stream, Cxt, WoT, b_out, out);
}

// Round 8
// 152.346 us; speedup vs baseline: 1.3089x; 1.1425x over previous
//
#include <hip/hip_runtime.h>
#include <hip/hip_bf16.h>

#define B_ 2
#define S_ 2048
#define D_ 1024
#define H_ 16
#define HD_ 64
#define KDIM 1024
#define QKVW 3072

typedef __attribute__((ext_vector_type(8))) short s16x8;
typedef __attribute__((ext_vector_type(8))) __bf16 bf16x8;
typedef __attribute__((ext_vector_type(4))) float f32x4;
typedef __attribute__((ext_vector_type(16))) float f32x16;
typedef __attribute__((ext_vector_type(4))) unsigned short u16x4;

__device__ __forceinline__ unsigned short f2bf(float f) {
  union { __bf16 b; unsigned short u; } v;
  v.b = (__bf16)f;
  return v.u;
}

__device__ __forceinline__ unsigned pk2(float lo, float hi) {
  union { unsigned short s[2]; unsigned u; } r;
  r.s[0] = f2bf(lo); r.s[1] = f2bf(hi);
  return r.u;
}

// permlane32_swap(a, b): HW swaps a[32+j] <-> b[j].
__device__ __forceinline__ void plswap2(unsigned& a_out, unsigned& b_out,
                                        unsigned a, unsigned b) {
  auto rr = __builtin_amdgcn_permlane32_swap(a, b, false, false);
  unsigned out[2];
  __builtin_memcpy(out, &rr, 8);
  a_out = out[0];
  b_out = out[1];
}

#define MFMA16(a, b, c) __builtin_amdgcn_mfma_f32_16x16x32_bf16((a), (b), (c), 0, 0, 0)
#define MFMA32(a, b, c) __builtin_amdgcn_mfma_f32_32x32x16_bf16((a), (b), (c), 0, 0, 0)

__device__ __forceinline__ void gll16(const void* g, void* l) {
  __builtin_amdgcn_global_load_lds(
      (const __attribute__((address_space(1))) void*)g,
      (__attribute__((address_space(3))) void*)l, 16, 0, 0);
}

// ---------------- X fp32 -> bf16
__global__ __launch_bounds__(256) void x2bf(const float* __restrict__ X,
                                            unsigned short* __restrict__ Xb) {
  const int i = (blockIdx.x * 256 + threadIdx.x) * 8;
  const float4 a = *reinterpret_cast<const float4*>(X + i);
  const float4 b = *reinterpret_cast<const float4*>(X + i + 4);
  u16x4 lo = {f2bf(a.x), f2bf(a.y), f2bf(a.z), f2bf(a.w)};
  u16x4 hi = {f2bf(b.x), f2bf(b.y), f2bf(b.z), f2bf(b.w)};
  *reinterpret_cast<u16x4*>(Xb + i) = lo;
  *reinterpret_cast<u16x4*>(Xb + i + 4) = hi;
}

// ---------------- transpose+convert: W[1024][N] fp32 -> Wt[N][1024] bf16
__global__ __launch_bounds__(256) void transpose_w(const float* __restrict__ W,
                                                   unsigned short* __restrict__ Wt,
                                                   int N) {
  __shared__ float T[64][65];
  const int k0 = blockIdx.y * 64, n0 = blockIdx.x * 64;
  const int t = threadIdx.x;
  const int lr = t >> 4, lc = (t & 15) * 4;
#pragma unroll
  for (int p = 0; p < 4; ++p) {
    const int r = lr + p * 16;
    const float4 v = *reinterpret_cast<const float4*>(W + (size_t)(k0 + r) * N + n0 + lc);
    T[r][lc + 0] = v.x; T[r][lc + 1] = v.y; T[r][lc + 2] = v.z; T[r][lc + 3] = v.w;
  }
  __syncthreads();
  const int wn = t >> 4, wk = (t & 15) * 4;
#pragma unroll
  for (int p = 0; p < 4; ++p) {
    const int n = wn + p * 16;
    u16x4 o = {f2bf(T[wk + 0][n]), f2bf(T[wk + 1][n]), f2bf(T[wk + 2][n]), f2bf(T[wk + 3][n])};
    *reinterpret_cast<u16x4*>(Wt + (size_t)(n0 + n) * 1024 + k0 + wk) = o;
  }
}

// ---------------- V columns of QKV -> Vt[b,h,hd,s]
__global__ __launch_bounds__(256) void vtrans(const unsigned short* __restrict__ QKVc,
                                              unsigned short* __restrict__ Vt) {
  __shared__ unsigned short T[64][72];
  const int s0 = blockIdx.x * 64;
  const int bh = blockIdx.y;
  const int bb = bh >> 4, hh = bh & 15;
  const int t = threadIdx.x;
  const size_t base = (size_t)bh * (S_ * HD_);
  const int r = t >> 3, c8 = (t & 7) * 8;
#pragma unroll
  for (int p = 0; p < 2; ++p)
    *reinterpret_cast<s16x8*>(&T[r + p * 32][c8]) =
        *reinterpret_cast<const s16x8*>(
            QKVc + (size_t)(bb * S_ + s0 + r + p * 32) * QKVW + 2048 + hh * 64 + c8);
  __syncthreads();
  const int hd = t & 63, sg = (t >> 6) * 8;
#pragma unroll
  for (int p = 0; p < 2; ++p) {
    unsigned short tmp[8];
#pragma unroll
    for (int j = 0; j < 8; ++j) tmp[j] = T[sg + p * 32 + j][hd];
    *reinterpret_cast<s16x8*>(Vt + base + (size_t)hd * S_ + s0 + sg + p * 32) =
        *reinterpret_cast<s16x8*>(tmp);
  }
}

// ---------------- QKV projection (gll16-staged) -> plain C[4096][3072] bf16 (+bias)
__global__ __launch_bounds__(256) void gemm_qkv(
    const unsigned short* __restrict__ Xb, const unsigned short* __restrict__ WT,
    const float* __restrict__ bias, unsigned short* __restrict__ Cq) {
  __shared__ __align__(16) unsigned short As[128 * 64];
  __shared__ __align__(16) unsigned short Bs[128 * 64];
  const int m0 = blockIdx.y * 128, n0 = blockIdx.x * 128;
  const int t = threadIdx.x;
  const int lane = t & 63, wid = t >> 6;
  const int wr = wid >> 1, wc = wid & 1;
  const int l15 = lane & 15, l16 = lane >> 4;
  const int srow = lane >> 3, scol = ((lane & 7) ^ srow) << 3;
  f32x4 acc[4][4] = {};
  for (int k0 = 0; k0 < KDIM; k0 += 64) {
#pragma unroll
    for (int c = 0; c < 4; ++c) {
      const int r8 = wid * 32 + c * 8;
      gll16(Xb + (size_t)(m0 + r8 + srow) * KDIM + k0 + scol, &As[r8 * 64]);
      gll16(WT + (size_t)(n0 + r8 + srow) * KDIM + k0 + scol, &Bs[r8 * 64]);
    }
    __syncthreads();
    const int key = (l15 & 7) << 4;
    const char* ab = (const char*)As + (wr * 64 + l15) * 128;
    const char* bb = (const char*)Bs + (wc * 64 + l15) * 128;
#pragma unroll
    for (int ks = 0; ks < 2; ++ks) {
      bf16x8 af[4], bfr[4];
#pragma unroll
      for (int m = 0; m < 4; ++m)
        af[m] = *(const bf16x8*)(ab + m * 2048 + ((ks * 64 + l16 * 16) ^ key));
#pragma unroll
      for (int n = 0; n < 4; ++n)
        bfr[n] = *(const bf16x8*)(bb + n * 2048 + ((ks * 64 + l16 * 16) ^ key));
#pragma unroll
      for (int m = 0; m < 4; ++m)
#pragma unroll
        for (int n = 0; n < 4; ++n)
          acc[m][n] = MFMA16(af[m], bfr[n], acc[m][n]);
    }
    __syncthreads();
  }
#pragma unroll
  for (int n = 0; n < 4; ++n) {
    const int col = n0 + wc * 64 + n * 16 + l15;
    const float bv = bias[col];
#pragma unroll
    for (int m = 0; m < 4; ++m) {
#pragma unroll
      for (int j = 0; j < 4; ++j) {
        const int row = m0 + wr * 64 + m * 16 + l16 * 4 + j;
        Cq[(size_t)row * QKVW + col] = f2bf(acc[m][n][j] + bv);
      }
    }
  }
}

// ---------------- Flash attention: 2-wave blocks, LDS dbuf K/V, counted-vmcnt pipeline.
// 1024 blocks: xcd=bi&7 -> 4 heads/XCD; 64-row supertile (wave=32 rows), heavy-first.
__global__ __launch_bounds__(128, 2) void attn(
    const unsigned short* __restrict__ QKVc, const unsigned short* __restrict__ Vt,
    unsigned short* __restrict__ Cxt) {
  __shared__ __align__(16) unsigned short Kl[2][4096];  // [kv 64][hd 64] swizzled
  __shared__ __align__(16) unsigned short Vl[2][4096];  // [hd 64][kv 64] swizzled
  const int bi = blockIdx.x;
  const int xcd = bi & 7, slot = bi >> 3;
  const int bh = xcd * 4 + (slot & 3);
  const int qt = 31 - (slot >> 2);           // 64-row supertile, heavy first
  const int ntile = qt + 1;
  const int t = threadIdx.x, lane = t & 63, w = t >> 6;
  const int l31 = lane & 31, h = lane >> 5;
  const int h8 = h * 8, h16 = h * 16, h4 = h * 4;
  const int bb = bh >> 4, hh = bh & 15;
  const size_t base = (size_t)bh * (S_ * HD_);
  const int qrow0 = qt * 64 + w * 32;        // this wave's 32 q-rows
  const bool lastfull = (w == 1);            // wave1's diag tile second half valid
  const float NEG = -1e30f;
  const float SCALE = 0.18033688011112042f;  // (1/8)*log2(e)
  const int srow = lane >> 3;
  const int scol = ((lane & 7) ^ srow) << 3;

  bf16x8 qf[4];
  {
    const unsigned short* qp =
        QKVc + (size_t)(bb * S_ + qrow0 + l31) * QKVW + hh * 64 + h8;
#pragma unroll
    for (int ks = 0; ks < 4; ++ks) qf[ks] = *reinterpret_cast<const bf16x8*>(qp + ks * 16);
  }
  f32x16 o0 = {}, o1 = {};
  float mrow = NEG, lrow = 0.f;

  // per wave: 4 K rows-chunks + 4 V rows-chunks = 8 gll16
#define STAGE(buf, kvb)                                                               \
  do {                                                                                \
    _Pragma("unroll") for (int c = 0; c < 4; ++c) {                                   \
      const int r8 = w * 32 + c * 8;                                                  \
      gll16(QKVc + (size_t)(bb * S_ + (kvb) + r8 + srow) * QKVW + 1024 + hh * 64 + scol, \
            &Kl[buf][r8 * 64]);                                                       \
      gll16(Vt + base + (size_t)(r8 + srow) * S_ + (kvb) + scol, &Vl[buf][r8 * 64]);  \
    }                                                                                 \
  } while (0)

#define COMPUTE(cur, kt)                                                             \
  do {                                                                               \
    const int kv0 = (kt) * 64;                                                       \
    const bool diag = ((kt) == ntile - 1);                                           \
    const bool full2 = !diag || lastfull;                                            \
    const char* kbase = (const char*)&Kl[cur][0];                                    \
    const char* vbase = (const char*)&Vl[cur][0];                                    \
    const int key = (l31 & 7) << 4;                                                  \
    f32x16 s0 = {}, s1 = {};                                                         \
    __builtin_amdgcn_s_setprio(1);                                                   \
    _Pragma("unroll") for (int ks = 0; ks < 4; ++ks) {                               \
      bf16x8 ka = *(const bf16x8*)(kbase + l31 * 128 + ((ks * 32 + h16) ^ key));     \
      s0 = MFMA32(ka, qf[ks], s0);                                                   \
    }                                                                                \
    if (full2) {                                                                     \
      _Pragma("unroll") for (int ks = 0; ks < 4; ++ks) {                             \
        bf16x8 kb = *(const bf16x8*)(kbase + (32 + l31) * 128 + ((ks * 32 + h16) ^ key)); \
        s1 = MFMA32(kb, qf[ks], s1);                                                 \
      }                                                                              \
    }                                                                                \
    __builtin_amdgcn_s_setprio(0);                                                   \
    if (diag) {                                                                      \
      const int lim0 = qrow0 + l31 - kv0;                                            \
      const int lim1 = lim0 - 32;                                                    \
      _Pragma("unroll") for (int r = 0; r < 16; ++r) {                               \
        const int cr = (r & 3) + 8 * (r >> 2) + h4;                                  \
        if (cr > lim0) s0[r] = NEG;                                                  \
        if (full2 && cr > lim1) s1[r] = NEG;                                         \
      }                                                                              \
    }                                                                                \
    float m8[8];                                                                     \
    _Pragma("unroll") for (int r = 0; r < 8; ++r) m8[r] = fmaxf(s0[r], s0[r + 8]);   \
    if (full2) {                                                                     \
      _Pragma("unroll") for (int r = 0; r < 8; ++r)                                  \
        m8[r] = fmaxf(m8[r], fmaxf(s1[r], s1[r + 8]));                               \
    }                                                                                \
    _Pragma("unroll") for (int st = 4; st > 0; st >>= 1)                             \
      _Pragma("unroll") for (int r = 0; r < st; ++r) m8[r] = fmaxf(m8[r], m8[r + st]);\
    const float pmax = fmaxf(m8[0], __shfl_xor(m8[0], 32)) * SCALE;                  \
    if (!__all(pmax - mrow <= 8.f)) {                                                \
      const float mn = fmaxf(mrow, pmax);                                            \
      const float al = exp2f(mrow - mn);                                             \
      mrow = mn;                                                                     \
      lrow *= al;                                                                    \
      _Pragma("unroll") for (int r = 0; r < 16; ++r) { o0[r] *= al; o1[r] *= al; }   \
    }                                                                                \
    _Pragma("unroll") for (int r = 0; r < 16; ++r)                                   \
      s0[r] = exp2f(fmaf(s0[r], SCALE, -mrow));                                      \
    if (full2) {                                                                     \
      _Pragma("unroll") for (int r = 0; r < 16; ++r)                                 \
        s1[r] = exp2f(fmaf(s1[r], SCALE, -mrow));                                    \
    }                                                                                \
    float p8[8];                                                                     \
    _Pragma("unroll") for (int r = 0; r < 8; ++r) p8[r] = s0[r] + s0[r + 8];         \
    if (full2) {                                                                     \
      _Pragma("unroll") for (int r = 0; r < 8; ++r) p8[r] += s1[r] + s1[r + 8];      \
    }                                                                                \
    _Pragma("unroll") for (int st = 4; st > 0; st >>= 1)                             \
      _Pragma("unroll") for (int r = 0; r < st; ++r) p8[r] += p8[r + st];            \
    lrow += p8[0] + __shfl_xor(p8[0], 32);                                           \
    bf16x8 pa[4];                                                                    \
    {                                                                                \
      union { unsigned u[4]; bf16x8 v; } uu;                                         \
      unsigned a0, a1, a2, a3, w0, w1, w2, w3;                                       \
      w0 = pk2(s0[0], s0[1]); w1 = pk2(s0[2], s0[3]);                                \
      w2 = pk2(s0[4], s0[5]); w3 = pk2(s0[6], s0[7]);                                \
      plswap2(a0, a2, w0, w2); plswap2(a1, a3, w1, w3);                              \
      uu.u[0] = a0; uu.u[1] = a1; uu.u[2] = a2; uu.u[3] = a3; pa[0] = uu.v;          \
      w0 = pk2(s0[8], s0[9]); w1 = pk2(s0[10], s0[11]);                              \
      w2 = pk2(s0[12], s0[13]); w3 = pk2(s0[14], s0[15]);                            \
      plswap2(a0, a2, w0, w2); plswap2(a1, a3, w1, w3);                              \
      uu.u[0] = a0; uu.u[1] = a1; uu.u[2] = a2; uu.u[3] = a3; pa[1] = uu.v;          \
      if (full2) {                                                                   \
        w0 = pk2(s1[0], s1[1]); w1 = pk2(s1[2], s1[3]);                              \
        w2 = pk2(s1[4], s1[5]); w3 = pk2(s1[6], s1[7]);                              \
        plswap2(a0, a2, w0, w2); plswap2(a1, a3, w1, w3);                            \
        uu.u[0] = a0; uu.u[1] = a1; uu.u[2] = a2; uu.u[3] = a3; pa[2] = uu.v;        \
        w0 = pk2(s1[8], s1[9]); w1 = pk2(s1[10], s1[11]);                            \
        w2 = pk2(s1[12], s1[13]); w3 = pk2(s1[14], s1[15]);                          \
        plswap2(a0, a2, w0, w2); plswap2(a1, a3, w1, w3);                            \
        uu.u[0] = a0; uu.u[1] = a1; uu.u[2] = a2; uu.u[3] = a3; pa[3] = uu.v;        \
      }                                                                              \
    }                                                                                \
    __builtin_amdgcn_s_setprio(1);                                                   \
    _Pragma("unroll") for (int hb = 0; hb < 2; ++hb) {                               \
      _Pragma("unroll") for (int ks = 0; ks < 4; ++ks)                               \
        if (full2 || ks < 2) {                                                       \
          bf16x8 va = *(const bf16x8*)(vbase + (hb * 32 + l31) * 128 +               \
                                       ((ks * 32 + h16) ^ key));                     \
          if (hb == 0) o0 = MFMA32(va, pa[ks], o0);                                  \
          else         o1 = MFMA32(va, pa[ks], o1);                                  \
        }                                                                            \
    }                                                                                \
    __builtin_amdgcn_s_setprio(0);                                                   \
  } while (0)

  STAGE(0, 0);
  for (int kt = 0; kt < ntile; ++kt) {
    const int cur = kt & 1;
    if (kt + 1 < ntile) {
      STAGE(cur ^ 1, (kt + 1) * 64);
      __asm__ volatile("s_waitcnt vmcnt(8)" ::: "memory");
    } else {
      __asm__ volatile("s_waitcnt vmcnt(0)" ::: "memory");
    }
    __builtin_amdgcn_s_barrier();        // cur tile's data visible to both waves
    COMPUTE(cur, kt);
    __builtin_amdgcn_s_barrier();        // all waves done reading cur before overwrite
  }

  // ---- epilogue: O^T -> LDS (own wave's 8KB) -> coalesced bf16 stores (Cxt [b,h,s,hd])
  __syncthreads();
  float* obuf = (float*)&Kl[w][0];
  const float rl = 1.0f / lrow;
#pragma unroll
  for (int r = 0; r < 16; ++r) {
    const int cr = (r & 3) + 8 * (r >> 2) + h4;
    obuf[l31 * 64 + (cr ^ ((l31 & 7) << 2))] = o0[r] * rl;
    obuf[l31 * 64 + ((32 + cr) ^ ((l31 & 7) << 2))] = o1[r] * rl;
  }
  __asm__ volatile("s_waitcnt lgkmcnt(0)" ::: "memory");
#pragma unroll
  for (int p = 0; p < 8; ++p) {
    const int r = (lane >> 4) + p * 4;
    const int ce = ((lane & 15) * 4) ^ ((r & 7) << 2);
    const f32x4 v = *reinterpret_cast<const f32x4*>(&obuf[r * 64 + ce]);
    u16x4 wv = {f2bf(v[0]), f2bf(v[1]), f2bf(v[2]), f2bf(v[3])};
    *reinterpret_cast<u16x4*>(&Cxt[base + (size_t)(qrow0 + r) * HD_ + (lane & 15) * 4]) = wv;
  }
}

// ---------------- Output projection (gll16-staged): out = Ctx @ WoT^T + bias (fp32)
// Ctx head-blocked [b][h][s][hd]; K-step 64 = one head plane.
__global__ __launch_bounds__(256) void gemm_out(
    const unsigned short* __restrict__ Cxt, const unsigned short* __restrict__ WT,
    const float* __restrict__ bias, float* __restrict__ out) {
  constexpr int NM = 1024;
  __shared__ __align__(16) unsigned short As[128 * 64];
  __shared__ __align__(16) unsigned short Bs[128 * 64];
  const int m0 = blockIdx.y * 128, n0 = blockIdx.x * 128;
  const int t = threadIdx.x;
  const int lane = t & 63, wid = t >> 6;
  const int wr = wid >> 1, wc = wid & 1;
  const int l15 = lane & 15, l16 = lane >> 4;
  const int srow = lane >> 3, scol = ((lane & 7) ^ srow) << 3;
  f32x4 acc[4][4] = {};
  for (int k0 = 0; k0 < KDIM; k0 += 64) {
    const int head = k0 >> 6;
#pragma unroll
    for (int c = 0; c < 4; ++c) {
      const int r8 = wid * 32 + c * 8;
      const int gr = m0 + r8 + srow;
      const unsigned short* asrc =
          Cxt + ((((size_t)(gr >> 11) * H_ + head) << 11) + (gr & 2047)) * HD_ + scol;
      gll16(asrc, &As[r8 * 64]);
      gll16(WT + (size_t)(n0 + r8 + srow) * KDIM + k0 + scol, &Bs[r8 * 64]);
    }
    __syncthreads();
    const int key = (l15 & 7) << 4;
    const char* ab = (const char*)As + (wr * 64 + l15) * 128;
    const char* bb = (const char*)Bs + (wc * 64 + l15) * 128;
#pragma unroll
    for (int ks = 0; ks < 2; ++ks) {
      bf16x8 af[4], bfr[4];
#pragma unroll
      for (int m = 0; m < 4; ++m)
        af[m] = *(const bf16x8*)(ab + m * 2048 + ((ks * 64 + l16 * 16) ^ key));
#pragma unroll
      for (int n = 0; n < 4; ++n)
        bfr[n] = *(const bf16x8*)(bb + n * 2048 + ((ks * 64 + l16 * 16) ^ key));
#pragma unroll
      for (int m = 0; m < 4; ++m)
#pragma unroll
        for (int n = 0; n < 4; ++n)
          acc[m][n] = MFMA16(af[m], bfr[n], acc[m][n]);
    }
    __syncthreads();
  }
#pragma unroll
  for (int n = 0; n < 4; ++n) {
    const int col = n0 + wc * 64 + n * 16 + l15;
    const float bv = bias[col];
#pragma unroll
    for (int m = 0; m < 4; ++m) {
#pragma unroll
      for (int j = 0; j < 4; ++j) {
        const int row = m0 + wr * 64 + m * 16 + l16 * 4 + j;
        out[(size_t)row * NM + col] = acc[m][n][j] + bv;
      }
    }
  }
}

extern "C" void kernel_launch(void* const* d_in, const int* in_sizes, int n_in,
                              void* d_out, int out_size, void* d_ws, size_t ws_size,
                              hipStream_t stream) {
  const float* x = (const float*)d_in[0];
  const float* w_qkv = (const float*)d_in[1];
  const float* b_qkv = (const float*)d_in[2];
  const float* w_out = (const float*)d_in[3];
  const float* b_out = (const float*)d_in[4];
  float* out = (float*)d_out;

  const size_t NTOK = (size_t)B_ * H_ * S_ * HD_;  // 4,194,304 elements
  unsigned short* QKVc = (unsigned short*)d_ws;     // [4096][3072]
  unsigned short* Vt = QKVc + (size_t)4096 * QKVW;  // V transposed [b,h,hd,s]
  unsigned short* WqT = Vt + NTOK;                  // [3072][1024]
  unsigned short* WoT = WqT + (size_t)3072 * 1024;  // [1024][1024]
  unsigned short* Xbf = WoT + (size_t)1024 * 1024;  // [4096][1024]
  unsigned short* Cxt = Xbf;                        // alias: Xbf dead before attn writes

  hipLaunchKernelGGL(x2bf, dim3(2048), dim3(256), 0, stream, x, Xbf);
  hipLaunchKernelGGL(transpose_w, dim3(48, 16), dim3(256), 0, stream, w_qkv, WqT, 3072);
  hipLaunchKernelGGL(transpose_w, dim3(16, 16), dim3(256), 0, stream, w_out, WoT, 1024);
  hipLaunchKernelGGL(gemm_qkv, dim3(24, 32), dim3(256), 0, stream, Xbf, WqT, b_qkv, QKVc);
  hipLaunchKernelGGL(vtrans, dim3(32, 32), dim3(256), 0, stream, QKVc, Vt);
  hipLaunchKernelGGL(attn, dim3(1024), dim3(128), 0, stream, QKVc, Vt, Cxt);
  hipLaunchKernelGGL(gemm_out, dim3(8, 32), dim3(256), 0, stream, Cxt, WoT, b_out, out);
}

// Round 9
// 132.085 us; speedup vs baseline: 1.5097x; 1.1534x over previous
//
#include <hip/hip_runtime.h>
#include <hip/hip_bf16.h>

#define B_ 2
#define S_ 2048
#define D_ 1024
#define H_ 16
#define HD_ 64
#define KDIM 1024
#define QKVW 3072

typedef __attribute__((ext_vector_type(8))) short s16x8;
typedef __attribute__((ext_vector_type(8))) __bf16 bf16x8;
typedef __attribute__((ext_vector_type(4))) float f32x4;
typedef __attribute__((ext_vector_type(16))) float f32x16;
typedef __attribute__((ext_vector_type(4))) unsigned short u16x4;

__device__ __forceinline__ unsigned short f2bf(float f) {
  union { __bf16 b; unsigned short u; } v;
  v.b = (__bf16)f;
  return v.u;
}

__device__ __forceinline__ unsigned pk2(float lo, float hi) {
  union { unsigned short s[2]; unsigned u; } r;
  r.s[0] = f2bf(lo); r.s[1] = f2bf(hi);
  return r.u;
}

// permlane32_swap(a, b): HW swaps a[32+j] <-> b[j].
__device__ __forceinline__ void plswap2(unsigned& a_out, unsigned& b_out,
                                        unsigned a, unsigned b) {
  auto rr = __builtin_amdgcn_permlane32_swap(a, b, false, false);
  unsigned out[2];
  __builtin_memcpy(out, &rr, 8);
  a_out = out[0];
  b_out = out[1];
}

#define MFMA16(a, b, c) __builtin_amdgcn_mfma_f32_16x16x32_bf16((a), (b), (c), 0, 0, 0)
#define MFMA32(a, b, c) __builtin_amdgcn_mfma_f32_32x32x16_bf16((a), (b), (c), 0, 0, 0)

__device__ __forceinline__ void gll16(const void* g, void* l) {
  __builtin_amdgcn_global_load_lds(
      (const __attribute__((address_space(1))) void*)g,
      (__attribute__((address_space(3))) void*)l, 16, 0, 0);
}

// ---------------- X fp32 -> bf16
__global__ __launch_bounds__(256) void x2bf(const float* __restrict__ X,
                                            unsigned short* __restrict__ Xb) {
  const int i = (blockIdx.x * 256 + threadIdx.x) * 8;
  const float4 a = *reinterpret_cast<const float4*>(X + i);
  const float4 b = *reinterpret_cast<const float4*>(X + i + 4);
  u16x4 lo = {f2bf(a.x), f2bf(a.y), f2bf(a.z), f2bf(a.w)};
  u16x4 hi = {f2bf(b.x), f2bf(b.y), f2bf(b.z), f2bf(b.w)};
  *reinterpret_cast<u16x4*>(Xb + i) = lo;
  *reinterpret_cast<u16x4*>(Xb + i + 4) = hi;
}

// ---------------- transpose+convert: W[1024][N] fp32 -> Wt[N][1024] bf16
__global__ __launch_bounds__(256) void transpose_w(const float* __restrict__ W,
                                                   unsigned short* __restrict__ Wt,
                                                   int N) {
  __shared__ float T[64][65];
  const int k0 = blockIdx.y * 64, n0 = blockIdx.x * 64;
  const int t = threadIdx.x;
  const int lr = t >> 4, lc = (t & 15) * 4;
#pragma unroll
  for (int p = 0; p < 4; ++p) {
    const int r = lr + p * 16;
    const float4 v = *reinterpret_cast<const float4*>(W + (size_t)(k0 + r) * N + n0 + lc);
    T[r][lc + 0] = v.x; T[r][lc + 1] = v.y; T[r][lc + 2] = v.z; T[r][lc + 3] = v.w;
  }
  __syncthreads();
  const int wn = t >> 4, wk = (t & 15) * 4;
#pragma unroll
  for (int p = 0; p < 4; ++p) {
    const int n = wn + p * 16;
    u16x4 o = {f2bf(T[wk + 0][n]), f2bf(T[wk + 1][n]), f2bf(T[wk + 2][n]), f2bf(T[wk + 3][n])};
    *reinterpret_cast<u16x4*>(Wt + (size_t)(n0 + n) * 1024 + k0 + wk) = o;
  }
}

// ---------------- V columns of QKV -> Vt[b,h,hd,s]
__global__ __launch_bounds__(256) void vtrans(const unsigned short* __restrict__ QKVc,
                                              unsigned short* __restrict__ Vt) {
  __shared__ unsigned short T[64][72];
  const int s0 = blockIdx.x * 64;
  const int bh = blockIdx.y;
  const int bb = bh >> 4, hh = bh & 15;
  const int t = threadIdx.x;
  const size_t base = (size_t)bh * (S_ * HD_);
  const int r = t >> 3, c8 = (t & 7) * 8;
#pragma unroll
  for (int p = 0; p < 2; ++p)
    *reinterpret_cast<s16x8*>(&T[r + p * 32][c8]) =
        *reinterpret_cast<const s16x8*>(
            QKVc + (size_t)(bb * S_ + s0 + r + p * 32) * QKVW + 2048 + hh * 64 + c8);
  __syncthreads();
  const int hd = t & 63, sg = (t >> 6) * 8;
#pragma unroll
  for (int p = 0; p < 2; ++p) {
    unsigned short tmp[8];
#pragma unroll
    for (int j = 0; j < 8; ++j) tmp[j] = T[sg + p * 32 + j][hd];
    *reinterpret_cast<s16x8*>(Vt + base + (size_t)hd * S_ + s0 + sg + p * 32) =
        *reinterpret_cast<s16x8*>(tmp);
  }
}

// ---------------- QKV projection (gll16-staged) -> plain C[4096][3072] bf16 (+bias)
__global__ __launch_bounds__(256) void gemm_qkv(
    const unsigned short* __restrict__ Xb, const unsigned short* __restrict__ WT,
    const float* __restrict__ bias, unsigned short* __restrict__ Cq) {
  __shared__ __align__(16) unsigned short As[128 * 64];
  __shared__ __align__(16) unsigned short Bs[128 * 64];
  const int m0 = blockIdx.y * 128, n0 = blockIdx.x * 128;
  const int t = threadIdx.x;
  const int lane = t & 63, wid = t >> 6;
  const int wr = wid >> 1, wc = wid & 1;
  const int l15 = lane & 15, l16 = lane >> 4;
  const int srow = lane >> 3, scol = ((lane & 7) ^ srow) << 3;
  f32x4 acc[4][4] = {};
  for (int k0 = 0; k0 < KDIM; k0 += 64) {
#pragma unroll
    for (int c = 0; c < 4; ++c) {
      const int r8 = wid * 32 + c * 8;
      gll16(Xb + (size_t)(m0 + r8 + srow) * KDIM + k0 + scol, &As[r8 * 64]);
      gll16(WT + (size_t)(n0 + r8 + srow) * KDIM + k0 + scol, &Bs[r8 * 64]);
    }
    __syncthreads();
    const int key = (l15 & 7) << 4;
    const char* ab = (const char*)As + (wr * 64 + l15) * 128;
    const char* bb = (const char*)Bs + (wc * 64 + l15) * 128;
#pragma unroll
    for (int ks = 0; ks < 2; ++ks) {
      bf16x8 af[4], bfr[4];
#pragma unroll
      for (int m = 0; m < 4; ++m)
        af[m] = *(const bf16x8*)(ab + m * 2048 + ((ks * 64 + l16 * 16) ^ key));
#pragma unroll
      for (int n = 0; n < 4; ++n)
        bfr[n] = *(const bf16x8*)(bb + n * 2048 + ((ks * 64 + l16 * 16) ^ key));
#pragma unroll
      for (int m = 0; m < 4; ++m)
#pragma unroll
        for (int n = 0; n < 4; ++n)
          acc[m][n] = MFMA16(af[m], bfr[n], acc[m][n]);
    }
    __syncthreads();
  }
#pragma unroll
  for (int n = 0; n < 4; ++n) {
    const int col = n0 + wc * 64 + n * 16 + l15;
    const float bv = bias[col];
#pragma unroll
    for (int m = 0; m < 4; ++m) {
#pragma unroll
      for (int j = 0; j < 4; ++j) {
        const int row = m0 + wr * 64 + m * 16 + l16 * 4 + j;
        Cq[(size_t)row * QKVW + col] = f2bf(acc[m][n][j] + bv);
      }
    }
  }
}

// ---------------- Flash attention: 4-wave blocks (2 q-waves x 2 kv-parity waves),
// fixed-exponent softmax, LDS pair double-buffer, counted vmcnt.
// 1024 blocks: xcd=bi&7 -> 4 heads/XCD; 64-row supertile, heavy-first.
__global__ __launch_bounds__(256, 2) void attn(
    const unsigned short* __restrict__ QKVc, const unsigned short* __restrict__ Vt,
    unsigned short* __restrict__ Cxt) {
  __shared__ __align__(16) unsigned short Kl[2][2][4096];  // [pairbuf][parity][kv64*hd64]
  __shared__ __align__(16) unsigned short Vl[2][2][4096];  // [pairbuf][parity][hd64*kv64]
  const int bi = blockIdx.x;
  const int xcd = bi & 7, slot = bi >> 3;
  const int bh = xcd * 4 + (slot & 3);
  const int qt = 31 - (slot >> 2);           // 64-row supertile, heavy first
  const int t = threadIdx.x, lane = t & 63, wid = t >> 6;
  const int qw = wid & 1, pw = wid >> 1;     // q-half, kv-parity
  const int l31 = lane & 31, h = lane >> 5;
  const int h8 = h * 8, h16 = h * 16, h4 = h * 4;
  const int bb = bh >> 4, hh = bh & 15;
  const size_t base = (size_t)bh * (S_ * HD_);
  const int q0 = qt * 64 + qw * 32;          // this wave's 32 q-rows
  const float NEG = -1e30f;
  const float SCALE = 0.18033688011112042f;  // (1/8)*log2(e)
  const float FM = 10.0f;                    // fixed softmax exponent (exp2 domain)
  const int srow = lane >> 3;
  const int scol = ((lane & 7) ^ srow) << 3;

  bf16x8 qf[4];
  {
    const unsigned short* qp =
        QKVc + (size_t)(bb * S_ + q0 + l31) * QKVW + hh * 64 + h8;
#pragma unroll
    for (int ks = 0; ks < 4; ++ks) qf[ks] = *reinterpret_cast<const bf16x8*>(qp + ks * 16);
  }
  f32x16 o0 = {}, o1 = {};
  float lacc[8] = {};

  // wave (qw,pw): qw==0 stages K, qw==1 stages V, for parity pw's tile. 8 gll16 each.
#define STAGE(buf, kvb)                                                               \
  do {                                                                                \
    if (qw == 0) {                                                                    \
      _Pragma("unroll") for (int c = 0; c < 8; ++c)                                   \
        gll16(QKVc + (size_t)(bb * S_ + (kvb) + c * 8 + srow) * QKVW + 1024 +         \
                  hh * 64 + scol,                                                     \
              &Kl[buf][pw][c * 8 * 64]);                                              \
    } else {                                                                          \
      _Pragma("unroll") for (int c = 0; c < 8; ++c)                                   \
        gll16(Vt + base + (size_t)(c * 8 + srow) * S_ + (kvb) + scol,                 \
              &Vl[buf][pw][c * 8 * 64]);                                              \
    }                                                                                 \
  } while (0)

#define COMPUTE(cb, tcur)                                                            \
  do {                                                                               \
    const int kv0 = (tcur) * 64;                                                     \
    const bool diag = (kv0 + 63 > q0);                                               \
    const bool full2 = (kv0 + 32 <= q0 + 31);                                        \
    const char* kbase = (const char*)&Kl[cb][pw][0];                                 \
    const char* vbase = (const char*)&Vl[cb][pw][0];                                 \
    const int key = (l31 & 7) << 4;                                                  \
    f32x16 s0 = {}, s1 = {};                                                         \
    __builtin_amdgcn_s_setprio(1);                                                   \
    _Pragma("unroll") for (int ks = 0; ks < 4; ++ks) {                               \
      bf16x8 ka = *(const bf16x8*)(kbase + l31 * 128 + ((ks * 32 + h16) ^ key));     \
      s0 = MFMA32(ka, qf[ks], s0);                                                   \
    }                                                                                \
    if (full2) {                                                                     \
      _Pragma("unroll") for (int ks = 0; ks < 4; ++ks) {                             \
        bf16x8 kb = *(const bf16x8*)(kbase + (32 + l31) * 128 + ((ks * 32 + h16) ^ key)); \
        s1 = MFMA32(kb, qf[ks], s1);                                                 \
      }                                                                              \
    }                                                                                \
    __builtin_amdgcn_s_setprio(0);                                                   \
    if (diag) {                                                                      \
      const int lim0 = q0 + l31 - kv0;                                               \
      const int lim1 = lim0 - 32;                                                    \
      _Pragma("unroll") for (int r = 0; r < 16; ++r) {                               \
        const int cr = (r & 3) + 8 * (r >> 2) + h4;                                  \
        if (cr > lim0) s0[r] = NEG;                                                  \
        if (full2 && cr > lim1) s1[r] = NEG;                                         \
      }                                                                              \
    }                                                                                \
    _Pragma("unroll") for (int r = 0; r < 16; ++r)                                   \
      s0[r] = exp2f(fmaf(s0[r], SCALE, -FM));                                        \
    if (full2) {                                                                     \
      _Pragma("unroll") for (int r = 0; r < 16; ++r)                                 \
        s1[r] = exp2f(fmaf(s1[r], SCALE, -FM));                                      \
    }                                                                                \
    _Pragma("unroll") for (int r = 0; r < 8; ++r) {                                  \
      float ps = s0[r] + s0[r + 8];                                                  \
      if (full2) ps += s1[r] + s1[r + 8];                                            \
      lacc[r] += ps;                                                                 \
    }                                                                                \
    bf16x8 pa[4];                                                                    \
    {                                                                                \
      union { unsigned u[4]; bf16x8 v; } uu;                                         \
      unsigned a0, a1, a2, a3, w0, w1, w2, w3;                                       \
      w0 = pk2(s0[0], s0[1]); w1 = pk2(s0[2], s0[3]);                                \
      w2 = pk2(s0[4], s0[5]); w3 = pk2(s0[6], s0[7]);                                \
      plswap2(a0, a2, w0, w2); plswap2(a1, a3, w1, w3);                              \
      uu.u[0] = a0; uu.u[1] = a1; uu.u[2] = a2; uu.u[3] = a3; pa[0] = uu.v;          \
      w0 = pk2(s0[8], s0[9]); w1 = pk2(s0[10], s0[11]);                              \
      w2 = pk2(s0[12], s0[13]); w3 = pk2(s0[14], s0[15]);                            \
      plswap2(a0, a2, w0, w2); plswap2(a1, a3, w1, w3);                              \
      uu.u[0] = a0; uu.u[1] = a1; uu.u[2] = a2; uu.u[3] = a3; pa[1] = uu.v;          \
      if (full2) {                                                                   \
        w0 = pk2(s1[0], s1[1]); w1 = pk2(s1[2], s1[3]);                              \
        w2 = pk2(s1[4], s1[5]); w3 = pk2(s1[6], s1[7]);                              \
        plswap2(a0, a2, w0, w2); plswap2(a1, a3, w1, w3);                            \
        uu.u[0] = a0; uu.u[1] = a1; uu.u[2] = a2; uu.u[3] = a3; pa[2] = uu.v;        \
        w0 = pk2(s1[8], s1[9]); w1 = pk2(s1[10], s1[11]);                            \
        w2 = pk2(s1[12], s1[13]); w3 = pk2(s1[14], s1[15]);                          \
        plswap2(a0, a2, w0, w2); plswap2(a1, a3, w1, w3);                            \
        uu.u[0] = a0; uu.u[1] = a1; uu.u[2] = a2; uu.u[3] = a3; pa[3] = uu.v;        \
      }                                                                              \
    }                                                                                \
    __builtin_amdgcn_s_setprio(1);                                                   \
    _Pragma("unroll") for (int hb = 0; hb < 2; ++hb) {                               \
      _Pragma("unroll") for (int ks = 0; ks < 4; ++ks)                               \
        if (full2 || ks < 2) {                                                       \
          bf16x8 va = *(const bf16x8*)(vbase + (hb * 32 + l31) * 128 +               \
                                       ((ks * 32 + h16) ^ key));                     \
          if (hb == 0) o0 = MFMA32(va, pa[ks], o0);                                  \
          else         o1 = MFMA32(va, pa[ks], o1);                                  \
        }                                                                            \
    }                                                                                \
    __builtin_amdgcn_s_setprio(0);                                                   \
  } while (0)

  const int npair = (qt >> 1) + 1;
  // prologue: stage pair 0 (own parity tile, if it exists)
  if (pw <= qt) STAGE(0, pw * 64);
  for (int p = 0; p < npair; ++p) {
    const int cb = p & 1;
    const int tnext = 2 * (p + 1) + pw;
    if (tnext <= qt) {
      STAGE(cb ^ 1, tnext * 64);
      __asm__ volatile("s_waitcnt vmcnt(8)" ::: "memory");
    } else {
      __asm__ volatile("s_waitcnt vmcnt(0)" ::: "memory");
    }
    __builtin_amdgcn_s_barrier();
    const int tcur = 2 * p + pw;
    if (tcur <= qt) COMPUTE(cb, tcur);
    __builtin_amdgcn_s_barrier();
  }

  // ---- row sums: tree + cross-half, once
  float lrow = 0.f;
#pragma unroll
  for (int r = 0; r < 8; ++r) lrow += lacc[r];
  lrow += __shfl_xor(lrow, 32);

  // ---- parity merge via LDS (exact: same fixed exponent)
  float* mb = (float*)&Kl[0][0][0];
  const int mi = qw * 2112 + lane * 33;
  if (pw == 1) {
#pragma unroll
    for (int r = 0; r < 16; ++r) { mb[mi + r] = o0[r]; mb[mi + 16 + r] = o1[r]; }
    mb[mi + 32] = lrow;
  }
  __syncthreads();
  if (pw == 1) return;
#pragma unroll
  for (int r = 0; r < 16; ++r) { o0[r] += mb[mi + r]; o1[r] += mb[mi + 16 + r]; }
  lrow += mb[mi + 32];

  // ---- epilogue: O^T -> LDS -> coalesced bf16 stores (Cxt [b,h,s,hd])
  float* obuf = (float*)&Vl[0][0][0] + (size_t)qw * 2048;
  const float rl = 1.0f / lrow;
#pragma unroll
  for (int r = 0; r < 16; ++r) {
    const int cr = (r & 3) + 8 * (r >> 2) + h4;
    obuf[l31 * 64 + (cr ^ ((l31 & 7) << 2))] = o0[r] * rl;
    obuf[l31 * 64 + ((32 + cr) ^ ((l31 & 7) << 2))] = o1[r] * rl;
  }
  __asm__ volatile("s_waitcnt lgkmcnt(0)" ::: "memory");
#pragma unroll
  for (int p = 0; p < 8; ++p) {
    const int r = (lane >> 4) + p * 4;
    const int ce = ((lane & 15) * 4) ^ ((r & 7) << 2);
    const f32x4 v = *reinterpret_cast<const f32x4*>(&obuf[r * 64 + ce]);
    u16x4 wv = {f2bf(v[0]), f2bf(v[1]), f2bf(v[2]), f2bf(v[3])};
    *reinterpret_cast<u16x4*>(&Cxt[base + (size_t)(q0 + r) * HD_ + (lane & 15) * 4]) = wv;
  }
}

// ---------------- Output projection (gll16-staged): out = Ctx @ WoT^T + bias (fp32)
// Ctx head-blocked [b][h][s][hd]; K-step 64 = one head plane.
__global__ __launch_bounds__(256) void gemm_out(
    const unsigned short* __restrict__ Cxt, const unsigned short* __restrict__ WT,
    const float* __restrict__ bias, float* __restrict__ out) {
  constexpr int NM = 1024;
  __shared__ __align__(16) unsigned short As[128 * 64];
  __shared__ __align__(16) unsigned short Bs[128 * 64];
  const int m0 = blockIdx.y * 128, n0 = blockIdx.x * 128;
  const int t = threadIdx.x;
  const int lane = t & 63, wid = t >> 6;
  const int wr = wid >> 1, wc = wid & 1;
  const int l15 = lane & 15, l16 = lane >> 4;
  const int srow = lane >> 3, scol = ((lane & 7) ^ srow) << 3;
  f32x4 acc[4][4] = {};
  for (int k0 = 0; k0 < KDIM; k0 += 64) {
    const int head = k0 >> 6;
#pragma unroll
    for (int c = 0; c < 4; ++c) {
      const int r8 = wid * 32 + c * 8;
      const int gr = m0 + r8 + srow;
      const unsigned short* asrc =
          Cxt + ((((size_t)(gr >> 11) * H_ + head) << 11) + (gr & 2047)) * HD_ + scol;
      gll16(asrc, &As[r8 * 64]);
      gll16(WT + (size_t)(n0 + r8 + srow) * KDIM + k0 + scol, &Bs[r8 * 64]);
    }
    __syncthreads();
    const int key = (l15 & 7) << 4;
    const char* ab = (const char*)As + (wr * 64 + l15) * 128;
    const char* bb = (const char*)Bs + (wc * 64 + l15) * 128;
#pragma unroll
    for (int ks = 0; ks < 2; ++ks) {
      bf16x8 af[4], bfr[4];
#pragma unroll
      for (int m = 0; m < 4; ++m)
        af[m] = *(const bf16x8*)(ab + m * 2048 + ((ks * 64 + l16 * 16) ^ key));
#pragma unroll
      for (int n = 0; n < 4; ++n)
        bfr[n] = *(const bf16x8*)(bb + n * 2048 + ((ks * 64 + l16 * 16) ^ key));
#pragma unroll
      for (int m = 0; m < 4; ++m)
#pragma unroll
        for (int n = 0; n < 4; ++n)
          acc[m][n] = MFMA16(af[m], bfr[n], acc[m][n]);
    }
    __syncthreads();
  }
#pragma unroll
  for (int n = 0; n < 4; ++n) {
    const int col = n0 + wc * 64 + n * 16 + l15;
    const float bv = bias[col];
#pragma unroll
    for (int m = 0; m < 4; ++m) {
#pragma unroll
      for (int j = 0; j < 4; ++j) {
        const int row = m0 + wr * 64 + m * 16 + l16 * 4 + j;
        out[(size_t)row * NM + col] = acc[m][n][j] + bv;
      }
    }
  }
}

extern "C" void kernel_launch(void* const* d_in, const int* in_sizes, int n_in,
                              void* d_out, int out_size, void* d_ws, size_t ws_size,
                              hipStream_t stream) {
  const float* x = (const float*)d_in[0];
  const float* w_qkv = (const float*)d_in[1];
  const float* b_qkv = (const float*)d_in[2];
  const float* w_out = (const float*)d_in[3];
  const float* b_out = (const float*)d_in[4];
  float* out = (float*)d_out;

  const size_t NTOK = (size_t)B_ * H_ * S_ * HD_;  // 4,194,304 elements
  unsigned short* QKVc = (unsigned short*)d_ws;     // [4096][3072]
  unsigned short* Vt = QKVc + (size_t)4096 * QKVW;  // V transposed [b,h,hd,s]
  unsigned short* WqT = Vt + NTOK;                  // [3072][1024]
  unsigned short* WoT = WqT + (size_t)3072 * 1024;  // [1024][1024]
  unsigned short* Xbf = WoT + (size_t)1024 * 1024;  // [4096][1024]
  unsigned short* Cxt = Xbf;                        // alias: Xbf dead before attn writes

  hipLaunchKernelGGL(x2bf, dim3(2048), dim3(256), 0, stream, x, Xbf);
  hipLaunchKernelGGL(transpose_w, dim3(48, 16), dim3(256), 0, stream, w_qkv, WqT, 3072);
  hipLaunchKernelGGL(transpose_w, dim3(16, 16), dim3(256), 0, stream, w_out, WoT, 1024);
  hipLaunchKernelGGL(gemm_qkv, dim3(24, 32), dim3(256), 0, stream, Xbf, WqT, b_qkv, QKVc);
  hipLaunchKernelGGL(vtrans, dim3(32, 32), dim3(256), 0, stream, QKVc, Vt);
  hipLaunchKernelGGL(attn, dim3(1024), dim3(256), 0, stream, QKVc, Vt, Cxt);
  hipLaunchKernelGGL(gemm_out, dim3(8, 32), dim3(256), 0, stream, Cxt, WoT, b_out, out);
}